// Round 4
// baseline (309.590 us; speedup 1.0000x reference)
//
#include <hip/hip_runtime.h>
#include <math.h>

// Problem constants (fixed by reference)
#define N_V  2048   // vertices
#define N_E  8192   // edges

// float4 elements per one-hot matrix [N_V, N_E] -> N_V * N_E/4
#define NE4            (N_V * (N_E / 4))     // 4,194,304
#define SCAN_ITER      8
#define SCAN_BPM       (NE4 / (256 * SCAN_ITER))   // 2048 blocks per matrix

static __device__ __forceinline__ float leaky(float x) {
    return x >= 0.f ? x : 0.01f * x;
}

static __device__ __forceinline__ void fma4(float4& c, float a, const float4& b) {
    c.x = fmaf(a, b.x, c.x);
    c.y = fmaf(a, b.y, c.y);
    c.z = fmaf(a, b.z, c.z);
    c.w = fmaf(a, b.w, c.w);
}

// ---- K1: scan one-hot vew1/vew2 -> src/dst indices ----
// Compile-time trip count, 8 independent float4 loads batched into registers
// before any testing -> 8 KB in flight per wave. ~128 MB total => ~20 us floor.
__global__ __launch_bounds__(256) void k_scan(const float4* __restrict__ vew1,
                                              const float4* __restrict__ vew2,
                                              int* __restrict__ src,
                                              int* __restrict__ dst)
{
    const int  bm     = blockIdx.x & (SCAN_BPM - 1);
    const bool second = blockIdx.x >= SCAN_BPM;
    const float4* __restrict__ p = second ? vew2 : vew1;
    int* __restrict__ arr        = second ? dst : src;

    const int base = bm * (256 * SCAN_ITER) + threadIdx.x;

    float4 v[SCAN_ITER];
#pragma unroll
    for (int k = 0; k < SCAN_ITER; ++k) v[k] = p[base + k * 256];

#pragma unroll
    for (int k = 0; k < SCAN_ITER; ++k) {
        const float4 q = v[k];
        if (q.x != 0.f || q.y != 0.f || q.z != 0.f || q.w != 0.f) {
            const int i  = base + k * 256;
            const int n  = i >> 11;            // row (vertex): E/4 = 2048 = 2^11
            const int e4 = (i & 2047) << 2;    // edge index base
            if (q.x != 0.f) arr[e4 + 0] = n;
            if (q.y != 0.f) arr[e4 + 1] = n;
            if (q.z != 0.f) arr[e4 + 2] = n;
            if (q.w != 0.f) arr[e4 + 3] = n;
        }
    }
}

// ---- K2: indeg[n] = #(src==n) + #(dst==n)  over e in [0, N_E) ----
__global__ __launch_bounds__(256) void k_indeg(const int* __restrict__ src,
                                               const int* __restrict__ dst,
                                               int* __restrict__ indeg)
{
    const int e = blockIdx.x * 256 + threadIdx.x;   // grid 32 -> 8192
    atomicAdd(&indeg[src[e]], 1);
    atomicAdd(&indeg[dst[e]], 1);
}

// ---- K3: per-vertex GEMMs with explicit register double-buffering. ----
// Thread t: column slice j0 = 4*(t&63) (float4), rows r0 = row0 + (t>>6)*2 + {0,1}.
// 8 rows/block, grid (256, 3) = 768 blocks = exactly 3/CU.
// B loads are float4 (1 KB/wave contiguous); ba/bb ping-pong keeps 8 float4
// loads (128 B/lane) in flight across each 128-FMA compute phase.
// mat 0: X = leaky(hv @ attend_w + b); mv_out = elu(X)
// mat 1: Au = hv @ Wu - Zpq            (Wu = link_w rows [0,256))
// mat 2: Av = hv @ Wv + Zpq + link_b   (Wv = link_w rows [262,518))
__global__ __launch_bounds__(256) void k_gemm(const float* __restrict__ hv,
                                              const float* __restrict__ attend_w,
                                              const float* __restrict__ attend_b,
                                              const float* __restrict__ link_w,
                                              const float* __restrict__ link_b,
                                              const float* __restrict__ p_ftr,
                                              const float* __restrict__ q_ftr,
                                              float* __restrict__ X,
                                              float* __restrict__ Au,
                                              float* __restrict__ Av,
                                              float* __restrict__ mv_out)
{
    const int mat  = blockIdx.y;                 // 0:X 1:Au 2:Av
    const int row0 = blockIdx.x * 8;
    const int jq   = threadIdx.x & 63;           // float4 column index (cols 4jq..4jq+3)
    const int r0   = row0 + (threadIdx.x >> 6) * 2;

    const float* __restrict__ B =
        (mat == 0) ? attend_w : (mat == 1 ? link_w : link_w + 262 * 256);
    const float4* __restrict__ B4 = (const float4*)B;

    const float* __restrict__ A0 = hv + r0 * 256;        // wave-uniform rows
    const float* __restrict__ A1 = A0 + 256;

    float4 acc0 = make_float4(0.f, 0.f, 0.f, 0.f);
    float4 acc1 = make_float4(0.f, 0.f, 0.f, 0.f);

    float4 ba[8], bb[8];
#pragma unroll
    for (int t = 0; t < 8; ++t) ba[t] = B4[t * 64 + jq];          // k = 0..7

    for (int ks = 0; ks < 256; ks += 16) {
        // issue loads for k = ks+8..ks+15
#pragma unroll
        for (int t = 0; t < 8; ++t) bb[t] = B4[(ks + 8 + t) * 64 + jq];
        // compute k = ks..ks+7 from ba
#pragma unroll
        for (int t = 0; t < 8; ++t) {
            const float a0 = A0[ks + t];
            const float a1 = A1[ks + t];
            fma4(acc0, a0, ba[t]);
            fma4(acc1, a1, ba[t]);
        }
        // issue loads for k = ks+16..ks+23 (wrap harmlessly at the end)
        const int kn = (ks + 16) & 255;
#pragma unroll
        for (int t = 0; t < 8; ++t) ba[t] = B4[(kn + t) * 64 + jq];
        // compute k = ks+8..ks+15 from bb
#pragma unroll
        for (int t = 0; t < 8; ++t) {
            const float a0 = A0[ks + 8 + t];
            const float a1 = A1[ks + 8 + t];
            fma4(acc0, a0, bb[t]);
            fma4(acc1, a1, bb[t]);
        }
    }

    if (mat == 0) {
        const float4 bias = *reinterpret_cast<const float4*>(attend_b + jq * 4);
        float4 a[2] = {acc0, acc1};
#pragma unroll
        for (int r = 0; r < 2; ++r) {
            float4 x;
            x.x = leaky(a[r].x + bias.x);
            x.y = leaky(a[r].y + bias.y);
            x.z = leaky(a[r].z + bias.z);
            x.w = leaky(a[r].w + bias.w);
            *reinterpret_cast<float4*>(X + (r0 + r) * 256 + jq * 4) = x;
            float4 m;
            m.x = (x.x > 0.f) ? x.x : expm1f(x.x);
            m.y = (x.y > 0.f) ? x.y : expm1f(x.y);
            m.z = (x.z > 0.f) ? x.z : expm1f(x.z);
            m.w = (x.w > 0.f) ? x.w : expm1f(x.w);
            *reinterpret_cast<float4*>(mv_out + (r0 + r) * 256 + jq * 4) = m;
        }
    } else {
        float4 w6[6];
#pragma unroll
        for (int t = 0; t < 6; ++t)
            w6[t] = *reinterpret_cast<const float4*>(link_w + (256 + t) * 256 + jq * 4);
        float4 lb = make_float4(0.f, 0.f, 0.f, 0.f);
        if (mat == 2) lb = *reinterpret_cast<const float4*>(link_b + jq * 4);
        float4 a[2] = {acc0, acc1};
#pragma unroll
        for (int r = 0; r < 2; ++r) {
            const int row = r0 + r;
            float4 z = make_float4(0.f, 0.f, 0.f, 0.f);
#pragma unroll
            for (int t = 0; t < 3; ++t) {
                fma4(z, p_ftr[row * 3 + t], w6[t]);
                fma4(z, q_ftr[row * 3 + t], w6[3 + t]);
            }
            float4 o;
            if (mat == 1) {
                o.x = a[r].x - z.x; o.y = a[r].y - z.y;
                o.z = a[r].z - z.z; o.w = a[r].w - z.w;
                *reinterpret_cast<float4*>(Au + row * 256 + jq * 4) = o;
            } else {
                o.x = a[r].x + z.x + lb.x; o.y = a[r].y + z.y + lb.y;
                o.z = a[r].z + z.z + lb.z; o.w = a[r].w + z.w + lb.w;
                *reinterpret_cast<float4*>(Av + row * 256 + jq * 4) = o;
            }
        }
    }
}

// ---- K4: sumAll[j] = sum_m indeg[m] * X[m][j]  (fallback for indeg==0) ----
__global__ __launch_bounds__(256) void k_sumall(const float* __restrict__ X,
                                                const int* __restrict__ indeg,
                                                float* __restrict__ sumAll)
{
    const int j  = threadIdx.x;
    const int m0 = blockIdx.x * 64;        // grid 32
    float s = 0.f;
    for (int m = m0; m < m0 + 64; ++m) {
        s = fmaf((float)indeg[m], X[m * 256 + j], s);
    }
    atomicAdd(&sumAll[j], s);
}

// ---- K5: fixup mv rows for indeg==0 vertices (rare; ~0-1 rows) ----
__global__ __launch_bounds__(256) void k_fix(const int* __restrict__ indeg,
                                             const float* __restrict__ sumAll,
                                             float* __restrict__ out)
{
    const int n = blockIdx.x;              // grid 2048
    if (indeg[n] != 0) return;
    const float v = sumAll[threadIdx.x] * (1.0f / (2.0f * N_E));
    out[n * 256 + threadIdx.x] = (v > 0.f) ? v : expm1f(v);
}

// ---- K6: me_ftr[e'] = leaky(Au[u[e']] + Av[v[e']]) ----
__global__ __launch_bounds__(256) void k_me(const int* __restrict__ src,
                                            const int* __restrict__ dst,
                                            const float* __restrict__ Au,
                                            const float* __restrict__ Av,
                                            float* __restrict__ out_me)
{
    const int t    = threadIdx.x;
    const int lane = t & 63;
    const int e    = blockIdx.x * 4 + (t >> 6);  // 4 edges per block, 1 wave each
    int u, v;
    if (e < N_E) { u = src[e]; v = dst[e]; }
    else         { u = dst[e - N_E]; v = src[e - N_E]; }
    const float4 a = *reinterpret_cast<const float4*>(&Au[u * 256 + lane * 4]);
    const float4 b = *reinterpret_cast<const float4*>(&Av[v * 256 + lane * 4]);
    float4 o;
    o.x = leaky(a.x + b.x);
    o.y = leaky(a.y + b.y);
    o.z = leaky(a.z + b.z);
    o.w = leaky(a.w + b.w);
    *reinterpret_cast<float4*>(&out_me[e * 256 + lane * 4]) = o;
}

extern "C" void kernel_launch(void* const* d_in, const int* in_sizes, int n_in,
                              void* d_out, int out_size, void* d_ws, size_t ws_size,
                              hipStream_t stream) {
    const float* hv       = (const float*)d_in[0];
    // d_in[1] he_ftr: unused (align path is dead code — softmax weights sum to 1)
    const float* p_ftr    = (const float*)d_in[2];
    const float* q_ftr    = (const float*)d_in[3];
    const float* vew1     = (const float*)d_in[4];
    const float* vew2     = (const float*)d_in[5];
    // d_in[6], d_in[7] veb1/veb2: redundant with vew
    const float* attend_w = (const float*)d_in[8];
    const float* attend_b = (const float*)d_in[9];
    // d_in[10], d_in[11] align_w/align_b: dead code
    const float* link_w   = (const float*)d_in[12];
    const float* link_b   = (const float*)d_in[13];

    float* out = (float*)d_out;
    float* ws  = (float*)d_ws;

    int*   src    = (int*)ws;              // [0, 8192)
    int*   dst    = src + N_E;             // [8192, 16384)
    int*   indeg  = dst + N_E;             // [16384, 18432)
    float* sumAll = ws + 18432;            // [18432, 18688)
    float* X      = ws + 32768;
    float* Au     = X + N_V * 256;
    float* Av     = Au + N_V * 256;

    // zero indeg + sumAll in one contiguous memset (ws is poisoned to 0xAA)
    hipMemsetAsync(indeg, 0, (N_V + 256) * sizeof(int), stream);

    k_scan<<<2 * SCAN_BPM, 256, 0, stream>>>((const float4*)vew1,
                                             (const float4*)vew2, src, dst);

    k_indeg<<<N_E / 256, 256, 0, stream>>>(src, dst, indeg);

    dim3 g2(N_V / 8, 3);
    k_gemm<<<g2, 256, 0, stream>>>(hv, attend_w, attend_b, link_w, link_b,
                                   p_ftr, q_ftr, X, Au, Av, out);

    k_sumall<<<32, 256, 0, stream>>>(X, indeg, sumAll);

    k_fix<<<N_V, 256, 0, stream>>>(indeg, sumAll, out);

    k_me<<<(2 * N_E) / 4, 256, 0, stream>>>(src, dst, Au, Av, out + N_V * 256);
}

// Round 6
// 293.473 us; speedup vs baseline: 1.0549x; 1.0549x over previous
//
#include <hip/hip_runtime.h>
#include <math.h>

// Problem constants (fixed by reference)
#define N_V  2048   // vertices
#define N_E  8192   // edges

// float4 elements per one-hot matrix [N_V, N_E] -> N_V * N_E/4
#define NE4            (N_V * (N_E / 4))     // 4,194,304
#define SCAN_ITER      8
#define SCAN_BPM       (NE4 / (256 * SCAN_ITER))   // 2048 blocks per matrix

static __device__ __forceinline__ float leaky(float x) {
    return x >= 0.f ? x : 0.01f * x;
}

static __device__ __forceinline__ void fma4(float4& c, float a, const float4& b) {
    c.x = fmaf(a, b.x, c.x);
    c.y = fmaf(a, b.y, c.y);
    c.z = fmaf(a, b.z, c.z);
    c.w = fmaf(a, b.w, c.w);
}

// ---- K1: scan one-hot vew1/vew2 -> src/dst indices ----
// Compile-time trip count, 8 independent float4 loads batched into registers
// before any testing -> 8 KB in flight per wave.
__global__ __launch_bounds__(256) void k_scan(const float4* __restrict__ vew1,
                                              const float4* __restrict__ vew2,
                                              int* __restrict__ src,
                                              int* __restrict__ dst)
{
    const int  bm     = blockIdx.x & (SCAN_BPM - 1);
    const bool second = blockIdx.x >= SCAN_BPM;
    const float4* __restrict__ p = second ? vew2 : vew1;
    int* __restrict__ arr        = second ? dst : src;

    const int base = bm * (256 * SCAN_ITER) + threadIdx.x;

    float4 v[SCAN_ITER];
#pragma unroll
    for (int k = 0; k < SCAN_ITER; ++k) v[k] = p[base + k * 256];

#pragma unroll
    for (int k = 0; k < SCAN_ITER; ++k) {
        const float4 q = v[k];
        if (q.x != 0.f || q.y != 0.f || q.z != 0.f || q.w != 0.f) {
            const int i  = base + k * 256;
            const int n  = i >> 11;            // row (vertex): E/4 = 2048 = 2^11
            const int e4 = (i & 2047) << 2;    // edge index base
            if (q.x != 0.f) arr[e4 + 0] = n;
            if (q.y != 0.f) arr[e4 + 1] = n;
            if (q.z != 0.f) arr[e4 + 2] = n;
            if (q.w != 0.f) arr[e4 + 3] = n;
        }
    }
}

// ---- K2: indeg[n] = #(src==n) + #(dst==n)  over e in [0, N_E) ----
__global__ __launch_bounds__(256) void k_indeg(const int* __restrict__ src,
                                               const int* __restrict__ dst,
                                               int* __restrict__ indeg)
{
    const int e = blockIdx.x * 256 + threadIdx.x;   // grid 32 -> 8192
    atomicAdd(&indeg[src[e]], 1);
    atomicAdd(&indeg[dst[e]], 1);
}

// ---- K3: per-vertex GEMMs: LDS-staged A + register-double-buffered B. ----
// r4 post-mortem: A reads were 512 per-thread L2 loads on the FMA dep chain
// (divergence analysis can't prove tid>>6 wave-uniform) AND the compiler
// capped VGPRs at 36, killing the B double-buffer. Fix: A-tile in LDS
// (ds_read_b128 broadcast at wave-uniform addr), __launch_bounds__(256,3)
// so the 64-VGPR B ping-pong stays resident (cap ~168).
// Thread t: cols 4*(t&63)..+3, local rows (t>>6)*2 + {0,1}. 8 rows/block,
// grid (256, 3) = 768 blocks = exactly 3/CU.
// mat 0: X = leaky(hv @ attend_w + b); mv_out = elu(X)
// mat 1: Au = hv @ Wu - Zpq            (Wu = link_w rows [0,256))
// mat 2: Av = hv @ Wv + Zpq + link_b   (Wv = link_w rows [262,518))
__global__ __launch_bounds__(256, 3) void k_gemm(const float* __restrict__ hv,
                                                 const float* __restrict__ attend_w,
                                                 const float* __restrict__ attend_b,
                                                 const float* __restrict__ link_w,
                                                 const float* __restrict__ link_b,
                                                 const float* __restrict__ p_ftr,
                                                 const float* __restrict__ q_ftr,
                                                 float* __restrict__ X,
                                                 float* __restrict__ Au,
                                                 float* __restrict__ Av,
                                                 float* __restrict__ mv_out)
{
    __shared__ float As[8 * 256];                // 8 KB A-tile

    const int mat  = blockIdx.y;                 // 0:X 1:Au 2:Av
    const int row0 = blockIdx.x * 8;
    const int tid  = threadIdx.x;

    {   // coalesced staging: 512 float4s, thread t takes t and t+256
        const float4* __restrict__ s4 = (const float4*)(hv + row0 * 256);
        float4* d4 = (float4*)As;
        d4[tid]       = s4[tid];
        d4[tid + 256] = s4[tid + 256];
    }
    __syncthreads();

    const int jq = tid & 63;                     // float4 column index
    const int rl = (tid >> 6) * 2;               // local row (0,2,4,6)
    const float* __restrict__ Arow0 = As + rl * 256;
    const float* __restrict__ Arow1 = Arow0 + 256;
    const int r0 = row0 + rl;

    const float* __restrict__ B =
        (mat == 0) ? attend_w : (mat == 1 ? link_w : link_w + 262 * 256);
    const float4* __restrict__ B4 = (const float4*)B;

    float4 acc0 = make_float4(0.f, 0.f, 0.f, 0.f);
    float4 acc1 = make_float4(0.f, 0.f, 0.f, 0.f);

    float4 ba[8], bb[8];
#pragma unroll
    for (int t = 0; t < 8; ++t) ba[t] = B4[t * 64 + jq];          // k = 0..7

    for (int ks = 0; ks < 256; ks += 16) {
        // issue B loads for k = ks+8..ks+15
#pragma unroll
        for (int t = 0; t < 8; ++t) bb[t] = B4[(ks + 8 + t) * 64 + jq];
        // compute k = ks..ks+7 from ba; A via LDS broadcast (ds_read_b128)
#pragma unroll
        for (int t4 = 0; t4 < 2; ++t4) {
            const float4 a0 = *reinterpret_cast<const float4*>(Arow0 + ks + t4 * 4);
            const float4 a1 = *reinterpret_cast<const float4*>(Arow1 + ks + t4 * 4);
            fma4(acc0, a0.x, ba[t4 * 4 + 0]);
            fma4(acc0, a0.y, ba[t4 * 4 + 1]);
            fma4(acc0, a0.z, ba[t4 * 4 + 2]);
            fma4(acc0, a0.w, ba[t4 * 4 + 3]);
            fma4(acc1, a1.x, ba[t4 * 4 + 0]);
            fma4(acc1, a1.y, ba[t4 * 4 + 1]);
            fma4(acc1, a1.z, ba[t4 * 4 + 2]);
            fma4(acc1, a1.w, ba[t4 * 4 + 3]);
        }
        // issue B loads for k = ks+16..ks+23 (wraps harmlessly at end)
        const int kn = (ks + 16) & 255;
#pragma unroll
        for (int t = 0; t < 8; ++t) ba[t] = B4[(kn + t) * 64 + jq];
        // compute k = ks+8..ks+15 from bb
#pragma unroll
        for (int t4 = 0; t4 < 2; ++t4) {
            const float4 a0 = *reinterpret_cast<const float4*>(Arow0 + ks + 8 + t4 * 4);
            const float4 a1 = *reinterpret_cast<const float4*>(Arow1 + ks + 8 + t4 * 4);
            fma4(acc0, a0.x, bb[t4 * 4 + 0]);
            fma4(acc0, a0.y, bb[t4 * 4 + 1]);
            fma4(acc0, a0.z, bb[t4 * 4 + 2]);
            fma4(acc0, a0.w, bb[t4 * 4 + 3]);
            fma4(acc1, a1.x, bb[t4 * 4 + 0]);
            fma4(acc1, a1.y, bb[t4 * 4 + 1]);
            fma4(acc1, a1.z, bb[t4 * 4 + 2]);
            fma4(acc1, a1.w, bb[t4 * 4 + 3]);
        }
    }

    if (mat == 0) {
        const float4 bias = *reinterpret_cast<const float4*>(attend_b + jq * 4);
        float4 a[2] = {acc0, acc1};
#pragma unroll
        for (int r = 0; r < 2; ++r) {
            float4 x;
            x.x = leaky(a[r].x + bias.x);
            x.y = leaky(a[r].y + bias.y);
            x.z = leaky(a[r].z + bias.z);
            x.w = leaky(a[r].w + bias.w);
            *reinterpret_cast<float4*>(X + (r0 + r) * 256 + jq * 4) = x;
            float4 m;
            m.x = (x.x > 0.f) ? x.x : expm1f(x.x);
            m.y = (x.y > 0.f) ? x.y : expm1f(x.y);
            m.z = (x.z > 0.f) ? x.z : expm1f(x.z);
            m.w = (x.w > 0.f) ? x.w : expm1f(x.w);
            *reinterpret_cast<float4*>(mv_out + (r0 + r) * 256 + jq * 4) = m;
        }
    } else {
        float4 w6[6];
#pragma unroll
        for (int t = 0; t < 6; ++t)
            w6[t] = *reinterpret_cast<const float4*>(link_w + (256 + t) * 256 + jq * 4);
        float4 lb = make_float4(0.f, 0.f, 0.f, 0.f);
        if (mat == 2) lb = *reinterpret_cast<const float4*>(link_b + jq * 4);
        float4 a[2] = {acc0, acc1};
#pragma unroll
        for (int r = 0; r < 2; ++r) {
            const int row = r0 + r;
            float4 z = make_float4(0.f, 0.f, 0.f, 0.f);
#pragma unroll
            for (int t = 0; t < 3; ++t) {
                fma4(z, p_ftr[row * 3 + t], w6[t]);
                fma4(z, q_ftr[row * 3 + t], w6[3 + t]);
            }
            float4 o;
            if (mat == 1) {
                o.x = a[r].x - z.x; o.y = a[r].y - z.y;
                o.z = a[r].z - z.z; o.w = a[r].w - z.w;
                *reinterpret_cast<float4*>(Au + row * 256 + jq * 4) = o;
            } else {
                o.x = a[r].x + z.x + lb.x; o.y = a[r].y + z.y + lb.y;
                o.z = a[r].z + z.z + lb.z; o.w = a[r].w + z.w + lb.w;
                *reinterpret_cast<float4*>(Av + row * 256 + jq * 4) = o;
            }
        }
    }
}

// ---- K4: sumAll[j] = sum_m indeg[m] * X[m][j]  (fallback for indeg==0) ----
__global__ __launch_bounds__(256) void k_sumall(const float* __restrict__ X,
                                                const int* __restrict__ indeg,
                                                float* __restrict__ sumAll)
{
    const int j  = threadIdx.x;
    const int m0 = blockIdx.x * 64;        // grid 32
    float s = 0.f;
    for (int m = m0; m < m0 + 64; ++m) {
        s = fmaf((float)indeg[m], X[m * 256 + j], s);
    }
    atomicAdd(&sumAll[j], s);
}

// ---- K5: fixup mv rows for indeg==0 vertices (rare; ~0-1 rows) ----
__global__ __launch_bounds__(256) void k_fix(const int* __restrict__ indeg,
                                             const float* __restrict__ sumAll,
                                             float* __restrict__ out)
{
    const int n = blockIdx.x;              // grid 2048
    if (indeg[n] != 0) return;
    const float v = sumAll[threadIdx.x] * (1.0f / (2.0f * N_E));
    out[n * 256 + threadIdx.x] = (v > 0.f) ? v : expm1f(v);
}

// ---- K6: me_ftr[e'] = leaky(Au[u[e']] + Av[v[e']]) ----
__global__ __launch_bounds__(256) void k_me(const int* __restrict__ src,
                                            const int* __restrict__ dst,
                                            const float* __restrict__ Au,
                                            const float* __restrict__ Av,
                                            float* __restrict__ out_me)
{
    const int t    = threadIdx.x;
    const int lane = t & 63;
    const int e    = blockIdx.x * 4 + (t >> 6);  // 4 edges per block, 1 wave each
    int u, v;
    if (e < N_E) { u = src[e]; v = dst[e]; }
    else         { u = dst[e - N_E]; v = src[e - N_E]; }
    const float4 a = *reinterpret_cast<const float4*>(&Au[u * 256 + lane * 4]);
    const float4 b = *reinterpret_cast<const float4*>(&Av[v * 256 + lane * 4]);
    float4 o;
    o.x = leaky(a.x + b.x);
    o.y = leaky(a.y + b.y);
    o.z = leaky(a.z + b.z);
    o.w = leaky(a.w + b.w);
    *reinterpret_cast<float4*>(&out_me[e * 256 + lane * 4]) = o;
}

extern "C" void kernel_launch(void* const* d_in, const int* in_sizes, int n_in,
                              void* d_out, int out_size, void* d_ws, size_t ws_size,
                              hipStream_t stream) {
    const float* hv       = (const float*)d_in[0];
    // d_in[1] he_ftr: unused (align path is dead code — softmax weights sum to 1)
    const float* p_ftr    = (const float*)d_in[2];
    const float* q_ftr    = (const float*)d_in[3];
    const float* vew1     = (const float*)d_in[4];
    const float* vew2     = (const float*)d_in[5];
    // d_in[6], d_in[7] veb1/veb2: redundant with vew
    const float* attend_w = (const float*)d_in[8];
    const float* attend_b = (const float*)d_in[9];
    // d_in[10], d_in[11] align_w/align_b: dead code
    const float* link_w   = (const float*)d_in[12];
    const float* link_b   = (const float*)d_in[13];

    float* out = (float*)d_out;
    float* ws  = (float*)d_ws;

    int*   src    = (int*)ws;              // [0, 8192)
    int*   dst    = src + N_E;             // [8192, 16384)
    int*   indeg  = dst + N_E;             // [16384, 18432)
    float* sumAll = ws + 18432;            // [18432, 18688)
    float* X      = ws + 32768;
    float* Au     = X + N_V * 256;
    float* Av     = Au + N_V * 256;

    // zero indeg + sumAll in one contiguous memset (ws is poisoned to 0xAA)
    hipMemsetAsync(indeg, 0, (N_V + 256) * sizeof(int), stream);

    k_scan<<<2 * SCAN_BPM, 256, 0, stream>>>((const float4*)vew1,
                                             (const float4*)vew2, src, dst);

    k_indeg<<<N_E / 256, 256, 0, stream>>>(src, dst, indeg);

    dim3 g2(N_V / 8, 3);
    k_gemm<<<g2, 256, 0, stream>>>(hv, attend_w, attend_b, link_w, link_b,
                                   p_ftr, q_ftr, X, Au, Av, out);

    k_sumall<<<32, 256, 0, stream>>>(X, indeg, sumAll);

    k_fix<<<N_V, 256, 0, stream>>>(indeg, sumAll, out);

    k_me<<<(2 * N_E) / 4, 256, 0, stream>>>(src, dst, Au, Av, out + N_V * 256);
}

// Round 8
// 289.252 us; speedup vs baseline: 1.0703x; 1.0146x over previous
//
#include <hip/hip_runtime.h>
#include <math.h>

// Problem constants (fixed by reference)
#define N_V  2048   // vertices
#define N_E  8192   // edges

// uint4 elements per one-hot matrix [N_V, N_E] -> N_V * N_E/4
#define NE4          (N_V * (N_E / 4))            // 4,194,304
#define SCAN_ITER    16
#define SCAN_BPM     (NE4 / (256 * SCAN_ITER))    // 1024 blocks per matrix
#define SCAN_BLOCKS  (2 * SCAN_BPM)               // 2048
#define GEMM_BLOCKS  768                          // (256 row-tiles) x (3 mats)
#define FUSED_BLOCKS (SCAN_BLOCKS + GEMM_BLOCKS)  // 2816 = 11 * 256

static __device__ __forceinline__ float leaky(float x) {
    return x >= 0.f ? x : 0.01f * x;
}

static __device__ __forceinline__ void fma4(float4& c, float a, const float4& b) {
    c.x = fmaf(a, b.x, c.x);
    c.y = fmaf(a, b.y, c.y);
    c.z = fmaf(a, b.z, c.z);
    c.w = fmaf(a, b.w, c.w);
}

// ---- K1: FUSED scan + gemm. ----
// Scan (memory-bound, VALU 2%) and gemm (VALU/LDS-bound) are independent;
// serialized they cost t_scan + t_gemm. One kernel, role by blockIdx,
// interleaved 8 scan : 3 gemm per 11-block period so both are co-resident
// from the start -> gemm hides under scan's memory stalls.
//
// Scan role: one-hot vew1/vew2 -> src/dst. 16 uint4 loads batched into
// registers (16 KB/wave in flight), integer nonzero tests.
// Gemm role (identical math to r6): LDS-staged A-tile + reg-double-buffered
// B, 8 rows/block, 3 mats.
//   mat 0: X = leaky(hv @ attend_w + b); mv_out = elu(X)
//   mat 1: Au = hv @ Wu - Zpq            (Wu = link_w rows [0,256))
//   mat 2: Av = hv @ Wv + Zpq + link_b   (Wv = link_w rows [262,518))
__global__ __launch_bounds__(256, 3) void k_scan_gemm(
        const uint4* __restrict__ vew1,
        const uint4* __restrict__ vew2,
        int* __restrict__ src,
        int* __restrict__ dst,
        const float* __restrict__ hv,
        const float* __restrict__ attend_w,
        const float* __restrict__ attend_b,
        const float* __restrict__ link_w,
        const float* __restrict__ link_b,
        const float* __restrict__ p_ftr,
        const float* __restrict__ q_ftr,
        float* __restrict__ X,
        float* __restrict__ Au,
        float* __restrict__ Av,
        float* __restrict__ mv_out)
{
    __shared__ float As[8 * 256];                // 8 KB (gemm role only)

    const int g   = blockIdx.x;
    const int per = g / 11;                      // 256 periods
    const int rem = g - per * 11;
    const int tid = threadIdx.x;

    if (rem < 8) {
        // ---------------- scan role: block ids 0..2047 ----------------
        const int  sid    = per * 8 + rem;
        const bool second = sid >= SCAN_BPM;
        const int  bm     = sid & (SCAN_BPM - 1);
        const uint4* __restrict__ p = second ? vew2 : vew1;
        int* __restrict__ arr       = second ? dst : src;

        const int base = bm * (256 * SCAN_ITER) + tid;

        uint4 v[SCAN_ITER];
#pragma unroll
        for (int k = 0; k < SCAN_ITER; ++k) v[k] = p[base + k * 256];

#pragma unroll
        for (int k = 0; k < SCAN_ITER; ++k) {
            const uint4 q = v[k];
            if (q.x | q.y | q.z | q.w) {
                const int i  = base + k * 256;
                const int n  = i >> 11;          // row: E/4 = 2048 = 2^11
                const int e4 = (i & 2047) << 2;  // edge index base
                if (q.x) arr[e4 + 0] = n;
                if (q.y) arr[e4 + 1] = n;
                if (q.z) arr[e4 + 2] = n;
                if (q.w) arr[e4 + 3] = n;
            }
        }
        return;
    }

    // ---------------- gemm role: 768 blocks ----------------
    const int gid  = per * 3 + (rem - 8);        // 0..767
    const int mat  = gid >> 8;                   // 0:X 1:Au 2:Av
    const int row0 = (gid & 255) * 8;

    {   // coalesced staging: 512 float4s, thread t takes t and t+256
        const float4* __restrict__ s4 = (const float4*)(hv + row0 * 256);
        float4* d4 = (float4*)As;
        d4[tid]       = s4[tid];
        d4[tid + 256] = s4[tid + 256];
    }
    __syncthreads();

    const int jq = tid & 63;                     // float4 column index
    const int rl = (tid >> 6) * 2;               // local row (0,2,4,6)
    const float* __restrict__ Arow0 = As + rl * 256;
    const float* __restrict__ Arow1 = Arow0 + 256;
    const int r0 = row0 + rl;

    const float* __restrict__ B =
        (mat == 0) ? attend_w : (mat == 1 ? link_w : link_w + 262 * 256);
    const float4* __restrict__ B4 = (const float4*)B;

    float4 acc0 = make_float4(0.f, 0.f, 0.f, 0.f);
    float4 acc1 = make_float4(0.f, 0.f, 0.f, 0.f);

    float4 ba[8], bb[8];
#pragma unroll
    for (int t = 0; t < 8; ++t) ba[t] = B4[t * 64 + jq];          // k = 0..7

    for (int ks = 0; ks < 256; ks += 16) {
        // issue B loads for k = ks+8..ks+15
#pragma unroll
        for (int t = 0; t < 8; ++t) bb[t] = B4[(ks + 8 + t) * 64 + jq];
        // compute k = ks..ks+7 from ba; A via LDS broadcast (ds_read_b128)
#pragma unroll
        for (int t4 = 0; t4 < 2; ++t4) {
            const float4 a0 = *reinterpret_cast<const float4*>(Arow0 + ks + t4 * 4);
            const float4 a1 = *reinterpret_cast<const float4*>(Arow1 + ks + t4 * 4);
            fma4(acc0, a0.x, ba[t4 * 4 + 0]);
            fma4(acc0, a0.y, ba[t4 * 4 + 1]);
            fma4(acc0, a0.z, ba[t4 * 4 + 2]);
            fma4(acc0, a0.w, ba[t4 * 4 + 3]);
            fma4(acc1, a1.x, ba[t4 * 4 + 0]);
            fma4(acc1, a1.y, ba[t4 * 4 + 1]);
            fma4(acc1, a1.z, ba[t4 * 4 + 2]);
            fma4(acc1, a1.w, ba[t4 * 4 + 3]);
        }
        // issue B loads for k = ks+16..ks+23 (wraps harmlessly at end)
        const int kn = (ks + 16) & 255;
#pragma unroll
        for (int t = 0; t < 8; ++t) ba[t] = B4[(kn + t) * 64 + jq];
        // compute k = ks+8..ks+15 from bb
#pragma unroll
        for (int t4 = 0; t4 < 2; ++t4) {
            const float4 a0 = *reinterpret_cast<const float4*>(Arow0 + ks + 8 + t4 * 4);
            const float4 a1 = *reinterpret_cast<const float4*>(Arow1 + ks + 8 + t4 * 4);
            fma4(acc0, a0.x, bb[t4 * 4 + 0]);
            fma4(acc0, a0.y, bb[t4 * 4 + 1]);
            fma4(acc0, a0.z, bb[t4 * 4 + 2]);
            fma4(acc0, a0.w, bb[t4 * 4 + 3]);
            fma4(acc1, a1.x, bb[t4 * 4 + 0]);
            fma4(acc1, a1.y, bb[t4 * 4 + 1]);
            fma4(acc1, a1.z, bb[t4 * 4 + 2]);
            fma4(acc1, a1.w, bb[t4 * 4 + 3]);
        }
    }

    if (mat == 0) {
        const float4 bias = *reinterpret_cast<const float4*>(attend_b + jq * 4);
        float4 a[2] = {acc0, acc1};
#pragma unroll
        for (int r = 0; r < 2; ++r) {
            float4 x;
            x.x = leaky(a[r].x + bias.x);
            x.y = leaky(a[r].y + bias.y);
            x.z = leaky(a[r].z + bias.z);
            x.w = leaky(a[r].w + bias.w);
            *reinterpret_cast<float4*>(X + (r0 + r) * 256 + jq * 4) = x;
            float4 m;
            m.x = (x.x > 0.f) ? x.x : expm1f(x.x);
            m.y = (x.y > 0.f) ? x.y : expm1f(x.y);
            m.z = (x.z > 0.f) ? x.z : expm1f(x.z);
            m.w = (x.w > 0.f) ? x.w : expm1f(x.w);
            *reinterpret_cast<float4*>(mv_out + (r0 + r) * 256 + jq * 4) = m;
        }
    } else {
        float4 w6[6];
#pragma unroll
        for (int t = 0; t < 6; ++t)
            w6[t] = *reinterpret_cast<const float4*>(link_w + (256 + t) * 256 + jq * 4);
        float4 lb = make_float4(0.f, 0.f, 0.f, 0.f);
        if (mat == 2) lb = *reinterpret_cast<const float4*>(link_b + jq * 4);
        float4 a[2] = {acc0, acc1};
#pragma unroll
        for (int r = 0; r < 2; ++r) {
            const int row = r0 + r;
            float4 z = make_float4(0.f, 0.f, 0.f, 0.f);
#pragma unroll
            for (int t = 0; t < 3; ++t) {
                fma4(z, p_ftr[row * 3 + t], w6[t]);
                fma4(z, q_ftr[row * 3 + t], w6[3 + t]);
            }
            float4 o;
            if (mat == 1) {
                o.x = a[r].x - z.x; o.y = a[r].y - z.y;
                o.z = a[r].z - z.z; o.w = a[r].w - z.w;
                *reinterpret_cast<float4*>(Au + row * 256 + jq * 4) = o;
            } else {
                o.x = a[r].x + z.x + lb.x; o.y = a[r].y + z.y + lb.y;
                o.z = a[r].z + z.z + lb.z; o.w = a[r].w + z.w + lb.w;
                *reinterpret_cast<float4*>(Av + row * 256 + jq * 4) = o;
            }
        }
    }
}

// ---- K2: indeg[n] = #(src==n) + #(dst==n)  over e in [0, N_E) ----
__global__ __launch_bounds__(256) void k_indeg(const int* __restrict__ src,
                                               const int* __restrict__ dst,
                                               int* __restrict__ indeg)
{
    const int e = blockIdx.x * 256 + threadIdx.x;   // grid 32 -> 8192
    atomicAdd(&indeg[src[e]], 1);
    atomicAdd(&indeg[dst[e]], 1);
}

// ---- K3: sumAll[j] = sum_m indeg[m] * X[m][j]  (fallback for indeg==0) ----
__global__ __launch_bounds__(256) void k_sumall(const float* __restrict__ X,
                                                const int* __restrict__ indeg,
                                                float* __restrict__ sumAll)
{
    const int j  = threadIdx.x;
    const int m0 = blockIdx.x * 64;        // grid 32
    float s = 0.f;
    for (int m = m0; m < m0 + 64; ++m) {
        s = fmaf((float)indeg[m], X[m * 256 + j], s);
    }
    atomicAdd(&sumAll[j], s);
}

// ---- K4: fixup mv rows for indeg==0 vertices (rare; ~0-1 rows) ----
__global__ __launch_bounds__(256) void k_fix(const int* __restrict__ indeg,
                                             const float* __restrict__ sumAll,
                                             float* __restrict__ out)
{
    const int n = blockIdx.x;              // grid 2048
    if (indeg[n] != 0) return;
    const float v = sumAll[threadIdx.x] * (1.0f / (2.0f * N_E));
    out[n * 256 + threadIdx.x] = (v > 0.f) ? v : expm1f(v);
}

// ---- K5: me_ftr[e'] = leaky(Au[u[e']] + Av[v[e']]) ----
__global__ __launch_bounds__(256) void k_me(const int* __restrict__ src,
                                            const int* __restrict__ dst,
                                            const float* __restrict__ Au,
                                            const float* __restrict__ Av,
                                            float* __restrict__ out_me)
{
    const int t    = threadIdx.x;
    const int lane = t & 63;
    const int e    = blockIdx.x * 4 + (t >> 6);  // 4 edges per block, 1 wave each
    int u, v;
    if (e < N_E) { u = src[e]; v = dst[e]; }
    else         { u = dst[e - N_E]; v = src[e - N_E]; }
    const float4 a = *reinterpret_cast<const float4*>(&Au[u * 256 + lane * 4]);
    const float4 b = *reinterpret_cast<const float4*>(&Av[v * 256 + lane * 4]);
    float4 o;
    o.x = leaky(a.x + b.x);
    o.y = leaky(a.y + b.y);
    o.z = leaky(a.z + b.z);
    o.w = leaky(a.w + b.w);
    *reinterpret_cast<float4*>(&out_me[e * 256 + lane * 4]) = o;
}

extern "C" void kernel_launch(void* const* d_in, const int* in_sizes, int n_in,
                              void* d_out, int out_size, void* d_ws, size_t ws_size,
                              hipStream_t stream) {
    const float* hv       = (const float*)d_in[0];
    // d_in[1] he_ftr: unused (align path is dead code — softmax weights sum to 1)
    const float* p_ftr    = (const float*)d_in[2];
    const float* q_ftr    = (const float*)d_in[3];
    const float* vew1     = (const float*)d_in[4];
    const float* vew2     = (const float*)d_in[5];
    // d_in[6], d_in[7] veb1/veb2: redundant with vew
    const float* attend_w = (const float*)d_in[8];
    const float* attend_b = (const float*)d_in[9];
    // d_in[10], d_in[11] align_w/align_b: dead code
    const float* link_w   = (const float*)d_in[12];
    const float* link_b   = (const float*)d_in[13];

    float* out = (float*)d_out;
    float* ws  = (float*)d_ws;

    int*   src    = (int*)ws;              // [0, 8192)
    int*   dst    = src + N_E;             // [8192, 16384)
    int*   indeg  = dst + N_E;             // [16384, 18432)
    float* sumAll = ws + 18432;            // [18432, 18688)
    float* X      = ws + 32768;
    float* Au     = X + N_V * 256;
    float* Av     = Au + N_V * 256;

    // zero indeg + sumAll in one contiguous memset (ws is poisoned to 0xAA)
    hipMemsetAsync(indeg, 0, (N_V + 256) * sizeof(int), stream);

    k_scan_gemm<<<FUSED_BLOCKS, 256, 0, stream>>>(
        (const uint4*)vew1, (const uint4*)vew2, src, dst,
        hv, attend_w, attend_b, link_w, link_b, p_ftr, q_ftr,
        X, Au, Av, out);

    k_indeg<<<N_E / 256, 256, 0, stream>>>(src, dst, indeg);

    k_sumall<<<32, 256, 0, stream>>>(X, indeg, sumAll);

    k_fix<<<N_V, 256, 0, stream>>>(indeg, sumAll, out);

    k_me<<<(2 * N_E) / 4, 256, 0, stream>>>(src, dst, Au, Av, out + N_V * 256);
}

// Round 10
// 282.493 us; speedup vs baseline: 1.0959x; 1.0239x over previous
//
#include <hip/hip_runtime.h>
#include <math.h>

// Problem constants (fixed by reference)
#define N_V  2048   // vertices
#define N_E  8192   // edges

// 16B elements per one-hot matrix [N_V, N_E] -> N_V * N_E/4
#define NE4        (N_V * (N_E / 4))          // 4,194,304
#define SCAN_ITER  8
#define SCAN_BPM   (NE4 / (256 * SCAN_ITER))  // 2048 blocks per matrix

// clang native vector (HIP's uint4 is a class; nontemporal builtin rejects it)
typedef unsigned int u32x4 __attribute__((ext_vector_type(4)));

static __device__ __forceinline__ float leaky(float x) {
    return x >= 0.f ? x : 0.01f * x;
}

static __device__ __forceinline__ void fma4(float4& c, float a, const float4& b) {
    c.x = fmaf(a, b.x, c.x);
    c.y = fmaf(a, b.y, c.y);
    c.z = fmaf(a, b.z, c.z);
    c.w = fmaf(a, b.w, c.w);
}

// ---- K1: scan one-hot vew1/vew2 -> src/dst indices ----
// r8 finding: batched vs serial loads both plateau at ~2.7 TB/s ==
// ~62 outstanding 64B lines/CU at ~900cy HBM latency -> L1-MSHR-bound.
// Nontemporal loads (nt path) to bypass L1 allocation on this zero-reuse
// stream.
__global__ __launch_bounds__(256) void k_scan(const u32x4* __restrict__ vew1,
                                              const u32x4* __restrict__ vew2,
                                              int* __restrict__ src,
                                              int* __restrict__ dst)
{
    const int  bm     = blockIdx.x & (SCAN_BPM - 1);
    const bool second = blockIdx.x >= SCAN_BPM;
    const u32x4* __restrict__ p = second ? vew2 : vew1;
    int* __restrict__ arr       = second ? dst : src;

    const int base = bm * (256 * SCAN_ITER) + threadIdx.x;

    u32x4 v[SCAN_ITER];
#pragma unroll
    for (int k = 0; k < SCAN_ITER; ++k)
        v[k] = __builtin_nontemporal_load(&p[base + k * 256]);

#pragma unroll
    for (int k = 0; k < SCAN_ITER; ++k) {
        const u32x4 q = v[k];
        if (q.x | q.y | q.z | q.w) {
            const int i  = base + k * 256;
            const int n  = i >> 11;            // row: E/4 = 2048 = 2^11
            const int e4 = (i & 2047) << 2;    // edge index base
            if (q.x) arr[e4 + 0] = n;
            if (q.y) arr[e4 + 1] = n;
            if (q.z) arr[e4 + 2] = n;
            if (q.w) arr[e4 + 3] = n;
        }
    }
}

// ---- K2: indeg[n] = #(src==n) + #(dst==n)  over e in [0, N_E) ----
__global__ __launch_bounds__(256) void k_indeg(const int* __restrict__ src,
                                               const int* __restrict__ dst,
                                               int* __restrict__ indeg)
{
    const int e = blockIdx.x * 256 + threadIdx.x;   // grid 32 -> 8192
    atomicAdd(&indeg[src[e]], 1);
    atomicAdd(&indeg[dst[e]], 1);
}

// ---- K3: per-vertex GEMMs. LDS-staged A + sched_barrier-pinned B batches. ----
// Every prior variant sat at ~45us because the compiler sank the 8-deep
// B-load batch into serial load->use (VGPR 36/40 proves it). Fix: pin each
// 8x dwordx4 load cluster with __builtin_amdgcn_sched_barrier(0) so FMAs
// can't be hoisted above it -> 8 loads forced live -> VGPR >= ~96.
// Thread t: cols 4*(t&63)..+3, local rows (t>>6)*2 + {0,1}. 8 rows/block,
// grid (256, 3) = 768 blocks = exactly 3/CU (12 waves/CU).
// mat 0: X = leaky(hv @ attend_w + b); mv_out = elu(X)
// mat 1: Au = hv @ Wu - Zpq            (Wu = link_w rows [0,256))
// mat 2: Av = hv @ Wv + Zpq + link_b   (Wv = link_w rows [262,518))
__global__ __launch_bounds__(256, 3) void k_gemm(const float* __restrict__ hv,
                                                 const float* __restrict__ attend_w,
                                                 const float* __restrict__ attend_b,
                                                 const float* __restrict__ link_w,
                                                 const float* __restrict__ link_b,
                                                 const float* __restrict__ p_ftr,
                                                 const float* __restrict__ q_ftr,
                                                 float* __restrict__ X,
                                                 float* __restrict__ Au,
                                                 float* __restrict__ Av,
                                                 float* __restrict__ mv_out)
{
    __shared__ float As[8 * 256];                // 8 KB A-tile

    const int mat  = blockIdx.y;                 // 0:X 1:Au 2:Av
    const int row0 = blockIdx.x * 8;
    const int tid  = threadIdx.x;

    {   // coalesced staging: 512 float4s, thread t takes t and t+256
        const float4* __restrict__ s4 = (const float4*)(hv + row0 * 256);
        float4* d4 = (float4*)As;
        d4[tid]       = s4[tid];
        d4[tid + 256] = s4[tid + 256];
    }
    __syncthreads();

    const int jq = tid & 63;                     // float4 column index
    const int rl = (tid >> 6) * 2;               // local row (0,2,4,6)
    const float* __restrict__ Arow0 = As + rl * 256;
    const float* __restrict__ Arow1 = Arow0 + 256;
    const int r0 = row0 + rl;

    const float* __restrict__ B =
        (mat == 0) ? attend_w : (mat == 1 ? link_w : link_w + 262 * 256);
    const float4* __restrict__ B4 = (const float4*)B;

    float4 acc0 = make_float4(0.f, 0.f, 0.f, 0.f);
    float4 acc1 = make_float4(0.f, 0.f, 0.f, 0.f);

    float4 ba[8], bb[8];
#pragma unroll
    for (int t = 0; t < 8; ++t) ba[t] = B4[t * 64 + jq];          // k = 0..7
    __builtin_amdgcn_sched_barrier(0);

    for (int ks = 0; ks < 256; ks += 16) {
        // issue B loads for k = ks+8..ks+15; pin them above the ba-FMAs
#pragma unroll
        for (int t = 0; t < 8; ++t) bb[t] = B4[(ks + 8 + t) * 64 + jq];
        __builtin_amdgcn_sched_barrier(0);
        // compute k = ks..ks+7 from ba; A via LDS broadcast (ds_read_b128)
#pragma unroll
        for (int t4 = 0; t4 < 2; ++t4) {
            const float4 a0 = *reinterpret_cast<const float4*>(Arow0 + ks + t4 * 4);
            const float4 a1 = *reinterpret_cast<const float4*>(Arow1 + ks + t4 * 4);
            fma4(acc0, a0.x, ba[t4 * 4 + 0]);
            fma4(acc0, a0.y, ba[t4 * 4 + 1]);
            fma4(acc0, a0.z, ba[t4 * 4 + 2]);
            fma4(acc0, a0.w, ba[t4 * 4 + 3]);
            fma4(acc1, a1.x, ba[t4 * 4 + 0]);
            fma4(acc1, a1.y, ba[t4 * 4 + 1]);
            fma4(acc1, a1.z, ba[t4 * 4 + 2]);
            fma4(acc1, a1.w, ba[t4 * 4 + 3]);
        }
        // issue B loads for k = ks+16..ks+23 (wraps harmlessly at end)
        const int kn = (ks + 16) & 255;
#pragma unroll
        for (int t = 0; t < 8; ++t) ba[t] = B4[(kn + t) * 64 + jq];
        __builtin_amdgcn_sched_barrier(0);
        // compute k = ks+8..ks+15 from bb
#pragma unroll
        for (int t4 = 0; t4 < 2; ++t4) {
            const float4 a0 = *reinterpret_cast<const float4*>(Arow0 + ks + 8 + t4 * 4);
            const float4 a1 = *reinterpret_cast<const float4*>(Arow1 + ks + 8 + t4 * 4);
            fma4(acc0, a0.x, bb[t4 * 4 + 0]);
            fma4(acc0, a0.y, bb[t4 * 4 + 1]);
            fma4(acc0, a0.z, bb[t4 * 4 + 2]);
            fma4(acc0, a0.w, bb[t4 * 4 + 3]);
            fma4(acc1, a1.x, bb[t4 * 4 + 0]);
            fma4(acc1, a1.y, bb[t4 * 4 + 1]);
            fma4(acc1, a1.z, bb[t4 * 4 + 2]);
            fma4(acc1, a1.w, bb[t4 * 4 + 3]);
        }
    }

    if (mat == 0) {
        const float4 bias = *reinterpret_cast<const float4*>(attend_b + jq * 4);
        float4 a[2] = {acc0, acc1};
#pragma unroll
        for (int r = 0; r < 2; ++r) {
            float4 x;
            x.x = leaky(a[r].x + bias.x);
            x.y = leaky(a[r].y + bias.y);
            x.z = leaky(a[r].z + bias.z);
            x.w = leaky(a[r].w + bias.w);
            *reinterpret_cast<float4*>(X + (r0 + r) * 256 + jq * 4) = x;
            float4 m;
            m.x = (x.x > 0.f) ? x.x : expm1f(x.x);
            m.y = (x.y > 0.f) ? x.y : expm1f(x.y);
            m.z = (x.z > 0.f) ? x.z : expm1f(x.z);
            m.w = (x.w > 0.f) ? x.w : expm1f(x.w);
            *reinterpret_cast<float4*>(mv_out + (r0 + r) * 256 + jq * 4) = m;
        }
    } else {
        float4 w6[6];
#pragma unroll
        for (int t = 0; t < 6; ++t)
            w6[t] = *reinterpret_cast<const float4*>(link_w + (256 + t) * 256 + jq * 4);
        float4 lb = make_float4(0.f, 0.f, 0.f, 0.f);
        if (mat == 2) lb = *reinterpret_cast<const float4*>(link_b + jq * 4);
        float4 a[2] = {acc0, acc1};
#pragma unroll
        for (int r = 0; r < 2; ++r) {
            const int row = r0 + r;
            float4 z = make_float4(0.f, 0.f, 0.f, 0.f);
#pragma unroll
            for (int t = 0; t < 3; ++t) {
                fma4(z, p_ftr[row * 3 + t], w6[t]);
                fma4(z, q_ftr[row * 3 + t], w6[3 + t]);
            }
            float4 o;
            if (mat == 1) {
                o.x = a[r].x - z.x; o.y = a[r].y - z.y;
                o.z = a[r].z - z.z; o.w = a[r].w - z.w;
                *reinterpret_cast<float4*>(Au + row * 256 + jq * 4) = o;
            } else {
                o.x = a[r].x + z.x + lb.x; o.y = a[r].y + z.y + lb.y;
                o.z = a[r].z + z.z + lb.z; o.w = a[r].w + z.w + lb.w;
                *reinterpret_cast<float4*>(Av + row * 256 + jq * 4) = o;
            }
        }
    }
}

// ---- K4: sumAll[j] = sum_m indeg[m] * X[m][j]  (fallback for indeg==0) ----
__global__ __launch_bounds__(256) void k_sumall(const float* __restrict__ X,
                                                const int* __restrict__ indeg,
                                                float* __restrict__ sumAll)
{
    const int j  = threadIdx.x;
    const int m0 = blockIdx.x * 64;        // grid 32
    float s = 0.f;
    for (int m = m0; m < m0 + 64; ++m) {
        s = fmaf((float)indeg[m], X[m * 256 + j], s);
    }
    atomicAdd(&sumAll[j], s);
}

// ---- K5: fixup mv rows for indeg==0 vertices (rare; ~0-1 rows) ----
__global__ __launch_bounds__(256) void k_fix(const int* __restrict__ indeg,
                                             const float* __restrict__ sumAll,
                                             float* __restrict__ out)
{
    const int n = blockIdx.x;              // grid 2048
    if (indeg[n] != 0) return;
    const float v = sumAll[threadIdx.x] * (1.0f / (2.0f * N_E));
    out[n * 256 + threadIdx.x] = (v > 0.f) ? v : expm1f(v);
}

// ---- K6: me_ftr[e'] = leaky(Au[u[e']] + Av[v[e']]) ----
__global__ __launch_bounds__(256) void k_me(const int* __restrict__ src,
                                            const int* __restrict__ dst,
                                            const float* __restrict__ Au,
                                            const float* __restrict__ Av,
                                            float* __restrict__ out_me)
{
    const int t    = threadIdx.x;
    const int lane = t & 63;
    const int e    = blockIdx.x * 4 + (t >> 6);  // 4 edges per block, 1 wave each
    int u, v;
    if (e < N_E) { u = src[e]; v = dst[e]; }
    else         { u = dst[e - N_E]; v = src[e - N_E]; }
    const float4 a = *reinterpret_cast<const float4*>(&Au[u * 256 + lane * 4]);
    const float4 b = *reinterpret_cast<const float4*>(&Av[v * 256 + lane * 4]);
    float4 o;
    o.x = leaky(a.x + b.x);
    o.y = leaky(a.y + b.y);
    o.z = leaky(a.z + b.z);
    o.w = leaky(a.w + b.w);
    *reinterpret_cast<float4*>(&out_me[e * 256 + lane * 4]) = o;
}

extern "C" void kernel_launch(void* const* d_in, const int* in_sizes, int n_in,
                              void* d_out, int out_size, void* d_ws, size_t ws_size,
                              hipStream_t stream) {
    const float* hv       = (const float*)d_in[0];
    // d_in[1] he_ftr: unused (align path is dead code — softmax weights sum to 1)
    const float* p_ftr    = (const float*)d_in[2];
    const float* q_ftr    = (const float*)d_in[3];
    const float* vew1     = (const float*)d_in[4];
    const float* vew2     = (const float*)d_in[5];
    // d_in[6], d_in[7] veb1/veb2: redundant with vew
    const float* attend_w = (const float*)d_in[8];
    const float* attend_b = (const float*)d_in[9];
    // d_in[10], d_in[11] align_w/align_b: dead code
    const float* link_w   = (const float*)d_in[12];
    const float* link_b   = (const float*)d_in[13];

    float* out = (float*)d_out;
    float* ws  = (float*)d_ws;

    int*   src    = (int*)ws;              // [0, 8192)
    int*   dst    = src + N_E;             // [8192, 16384)
    int*   indeg  = dst + N_E;             // [16384, 18432)
    float* sumAll = ws + 18432;            // [18432, 18688)
    float* X      = ws + 32768;
    float* Au     = X + N_V * 256;
    float* Av     = Au + N_V * 256;

    // zero indeg + sumAll in one contiguous memset (ws is poisoned to 0xAA)
    (void)hipMemsetAsync(indeg, 0, (N_V + 256) * sizeof(int), stream);

    k_scan<<<2 * SCAN_BPM, 256, 0, stream>>>((const u32x4*)vew1,
                                             (const u32x4*)vew2, src, dst);

    k_gemm<<<dim3(N_V / 8, 3), 256, 0, stream>>>(hv, attend_w, attend_b,
                                                 link_w, link_b, p_ftr, q_ftr,
                                                 X, Au, Av, out);

    k_indeg<<<N_E / 256, 256, 0, stream>>>(src, dst, indeg);

    k_sumall<<<32, 256, 0, stream>>>(X, indeg, sumAll);

    k_fix<<<N_V, 256, 0, stream>>>(indeg, sumAll, out);

    k_me<<<(2 * N_E) / 4, 256, 0, stream>>>(src, dst, Au, Av, out + N_V * 256);
}

// Round 11
// 282.086 us; speedup vs baseline: 1.0975x; 1.0014x over previous
//
#include <hip/hip_runtime.h>
#include <math.h>

// Problem constants (fixed by reference)
#define N_V  2048   // vertices
#define N_E  8192   // edges

// 16B elements per one-hot matrix [N_V, N_E] -> N_V * N_E/4
#define NE4        (N_V * (N_E / 4))          // 4,194,304
#define SCAN_ITER  8
#define SCAN_BPM   (NE4 / (256 * SCAN_ITER))  // 2048 blocks per matrix

#define GEMM_ROWS  16                          // rows per block (4 per thread)

// clang native vector (HIP's uint4 is a class; nontemporal builtin rejects it)
typedef unsigned int u32x4 __attribute__((ext_vector_type(4)));

static __device__ __forceinline__ float leaky(float x) {
    return x >= 0.f ? x : 0.01f * x;
}

static __device__ __forceinline__ void fma4(float4& c, float a, const float4& b) {
    c.x = fmaf(a, b.x, c.x);
    c.y = fmaf(a, b.y, c.y);
    c.z = fmaf(a, b.z, c.z);
    c.w = fmaf(a, b.w, c.w);
}

// ---- K1: scan one-hot vew1/vew2 -> src/dst indices ----
// nt loads bypass L1 allocation on this zero-reuse stream (r10: dropped
// k_scan below 42us, exact value TBD this round).
__global__ __launch_bounds__(256) void k_scan(const u32x4* __restrict__ vew1,
                                              const u32x4* __restrict__ vew2,
                                              int* __restrict__ src,
                                              int* __restrict__ dst)
{
    const int  bm     = blockIdx.x & (SCAN_BPM - 1);
    const bool second = blockIdx.x >= SCAN_BPM;
    const u32x4* __restrict__ p = second ? vew2 : vew1;
    int* __restrict__ arr       = second ? dst : src;

    const int base = bm * (256 * SCAN_ITER) + threadIdx.x;

    u32x4 v[SCAN_ITER];
#pragma unroll
    for (int k = 0; k < SCAN_ITER; ++k)
        v[k] = __builtin_nontemporal_load(&p[base + k * 256]);

#pragma unroll
    for (int k = 0; k < SCAN_ITER; ++k) {
        const u32x4 q = v[k];
        if (q.x | q.y | q.z | q.w) {
            const int i  = base + k * 256;
            const int n  = i >> 11;            // row: E/4 = 2048 = 2^11
            const int e4 = (i & 2047) << 2;    // edge index base
            if (q.x) arr[e4 + 0] = n;
            if (q.y) arr[e4 + 1] = n;
            if (q.z) arr[e4 + 2] = n;
            if (q.w) arr[e4 + 3] = n;
        }
    }
}

// ---- K2: indeg[n] = #(src==n) + #(dst==n)  over e in [0, N_E) ----
__global__ __launch_bounds__(256) void k_indeg(const int* __restrict__ src,
                                               const int* __restrict__ dst,
                                               int* __restrict__ indeg)
{
    const int e = blockIdx.x * 256 + threadIdx.x;   // grid 32 -> 8192
    atomicAdd(&indeg[src[e]], 1);
    atomicAdd(&indeg[dst[e]], 1);
}

// ---- K3: per-vertex GEMMs, 16 rows/block (4 per thread). ----
// r10 post-mortem: sched_barrier got the buffers live (VGPR 84) but time
// stayed 43us. Real causes: grid=768 capped occupancy at 3 blk/CU AND each
// thread read the full 256-row B stripe for only 2 output rows (load:FMA
// 1:8). Fix: 16 rows/block -> per-phase compute 256cy (covers ~200cy L2
// latency in ONE wave), B traffic halves (96MB total), FMA:load 16:1.
// Grid (128,3)=384 blocks, __launch_bounds__(256,4) (VGPR cap 128, need
// ~115: ba/bb 64 + acc 16 + A 16 + addr).
// mat 0: X = leaky(hv @ attend_w + b); mv_out = elu(X)
// mat 1: Au = hv @ Wu - Zpq            (Wu = link_w rows [0,256))
// mat 2: Av = hv @ Wv + Zpq + link_b   (Wv = link_w rows [262,518))
__global__ __launch_bounds__(256, 4) void k_gemm(const float* __restrict__ hv,
                                                 const float* __restrict__ attend_w,
                                                 const float* __restrict__ attend_b,
                                                 const float* __restrict__ link_w,
                                                 const float* __restrict__ link_b,
                                                 const float* __restrict__ p_ftr,
                                                 const float* __restrict__ q_ftr,
                                                 float* __restrict__ X,
                                                 float* __restrict__ Au,
                                                 float* __restrict__ Av,
                                                 float* __restrict__ mv_out)
{
    __shared__ float As[GEMM_ROWS * 256];        // 16 KB A-tile

    const int mat  = blockIdx.y;                 // 0:X 1:Au 2:Av
    const int row0 = blockIdx.x * GEMM_ROWS;
    const int tid  = threadIdx.x;

    {   // coalesced staging: 1024 float4s, 4 per thread
        const float4* __restrict__ s4 = (const float4*)(hv + row0 * 256);
        float4* d4 = (float4*)As;
#pragma unroll
        for (int t = 0; t < 4; ++t) d4[tid + t * 256] = s4[tid + t * 256];
    }
    __syncthreads();

    const int jq = tid & 63;                     // float4 column index
    const int rl = (tid >> 6) * 4;               // local row base (0,4,8,12)
    const float* __restrict__ Ar[4] = {
        As + (rl + 0) * 256, As + (rl + 1) * 256,
        As + (rl + 2) * 256, As + (rl + 3) * 256 };
    const int r0 = row0 + rl;

    const float* __restrict__ B =
        (mat == 0) ? attend_w : (mat == 1 ? link_w : link_w + 262 * 256);
    const float4* __restrict__ B4 = (const float4*)B;

    float4 acc[4];
#pragma unroll
    for (int r = 0; r < 4; ++r) acc[r] = make_float4(0.f, 0.f, 0.f, 0.f);

    float4 ba[8], bb[8];
#pragma unroll
    for (int t = 0; t < 8; ++t) ba[t] = B4[t * 64 + jq];          // k = 0..7
    __builtin_amdgcn_sched_barrier(0);

    for (int ks = 0; ks < 256; ks += 16) {
        // issue B loads for k = ks+8..ks+15; pin them above the ba-FMAs
#pragma unroll
        for (int t = 0; t < 8; ++t) bb[t] = B4[(ks + 8 + t) * 64 + jq];
        __builtin_amdgcn_sched_barrier(0);
        // compute k = ks..ks+7 from ba; A via LDS broadcast (ds_read_b128)
#pragma unroll
        for (int t4 = 0; t4 < 2; ++t4) {
#pragma unroll
            for (int r = 0; r < 4; ++r) {
                const float4 a = *reinterpret_cast<const float4*>(Ar[r] + ks + t4 * 4);
                fma4(acc[r], a.x, ba[t4 * 4 + 0]);
                fma4(acc[r], a.y, ba[t4 * 4 + 1]);
                fma4(acc[r], a.z, ba[t4 * 4 + 2]);
                fma4(acc[r], a.w, ba[t4 * 4 + 3]);
            }
        }
        // issue B loads for k = ks+16..ks+23 (wraps harmlessly at end)
        const int kn = (ks + 16) & 255;
#pragma unroll
        for (int t = 0; t < 8; ++t) ba[t] = B4[(kn + t) * 64 + jq];
        __builtin_amdgcn_sched_barrier(0);
        // compute k = ks+8..ks+15 from bb
#pragma unroll
        for (int t4 = 0; t4 < 2; ++t4) {
#pragma unroll
            for (int r = 0; r < 4; ++r) {
                const float4 a = *reinterpret_cast<const float4*>(Ar[r] + ks + 8 + t4 * 4);
                fma4(acc[r], a.x, bb[t4 * 4 + 0]);
                fma4(acc[r], a.y, bb[t4 * 4 + 1]);
                fma4(acc[r], a.z, bb[t4 * 4 + 2]);
                fma4(acc[r], a.w, bb[t4 * 4 + 3]);
            }
        }
    }

    if (mat == 0) {
        const float4 bias = *reinterpret_cast<const float4*>(attend_b + jq * 4);
#pragma unroll
        for (int r = 0; r < 4; ++r) {
            float4 x;
            x.x = leaky(acc[r].x + bias.x);
            x.y = leaky(acc[r].y + bias.y);
            x.z = leaky(acc[r].z + bias.z);
            x.w = leaky(acc[r].w + bias.w);
            *reinterpret_cast<float4*>(X + (r0 + r) * 256 + jq * 4) = x;
            float4 m;
            m.x = (x.x > 0.f) ? x.x : expm1f(x.x);
            m.y = (x.y > 0.f) ? x.y : expm1f(x.y);
            m.z = (x.z > 0.f) ? x.z : expm1f(x.z);
            m.w = (x.w > 0.f) ? x.w : expm1f(x.w);
            *reinterpret_cast<float4*>(mv_out + (r0 + r) * 256 + jq * 4) = m;
        }
    } else {
        float4 w6[6];
#pragma unroll
        for (int t = 0; t < 6; ++t)
            w6[t] = *reinterpret_cast<const float4*>(link_w + (256 + t) * 256 + jq * 4);
        float4 lb = make_float4(0.f, 0.f, 0.f, 0.f);
        if (mat == 2) lb = *reinterpret_cast<const float4*>(link_b + jq * 4);
#pragma unroll
        for (int r = 0; r < 4; ++r) {
            const int row = r0 + r;
            float4 z = make_float4(0.f, 0.f, 0.f, 0.f);
#pragma unroll
            for (int t = 0; t < 3; ++t) {
                fma4(z, p_ftr[row * 3 + t], w6[t]);
                fma4(z, q_ftr[row * 3 + t], w6[3 + t]);
            }
            float4 o;
            if (mat == 1) {
                o.x = acc[r].x - z.x; o.y = acc[r].y - z.y;
                o.z = acc[r].z - z.z; o.w = acc[r].w - z.w;
                *reinterpret_cast<float4*>(Au + row * 256 + jq * 4) = o;
            } else {
                o.x = acc[r].x + z.x + lb.x; o.y = acc[r].y + z.y + lb.y;
                o.z = acc[r].z + z.z + lb.z; o.w = acc[r].w + z.w + lb.w;
                *reinterpret_cast<float4*>(Av + row * 256 + jq * 4) = o;
            }
        }
    }
}

// ---- K4: sumAll[j] = sum_m indeg[m] * X[m][j]  (fallback for indeg==0) ----
__global__ __launch_bounds__(256) void k_sumall(const float* __restrict__ X,
                                                const int* __restrict__ indeg,
                                                float* __restrict__ sumAll)
{
    const int j  = threadIdx.x;
    const int m0 = blockIdx.x * 64;        // grid 32
    float s = 0.f;
    for (int m = m0; m < m0 + 64; ++m) {
        s = fmaf((float)indeg[m], X[m * 256 + j], s);
    }
    atomicAdd(&sumAll[j], s);
}

// ---- K5: fixup mv rows for indeg==0 vertices (rare; ~0-1 rows) ----
__global__ __launch_bounds__(256) void k_fix(const int* __restrict__ indeg,
                                             const float* __restrict__ sumAll,
                                             float* __restrict__ out)
{
    const int n = blockIdx.x;              // grid 2048
    if (indeg[n] != 0) return;
    const float v = sumAll[threadIdx.x] * (1.0f / (2.0f * N_E));
    out[n * 256 + threadIdx.x] = (v > 0.f) ? v : expm1f(v);
}

// ---- K6: me_ftr[e'] = leaky(Au[u[e']] + Av[v[e']]) ----
__global__ __launch_bounds__(256) void k_me(const int* __restrict__ src,
                                            const int* __restrict__ dst,
                                            const float* __restrict__ Au,
                                            const float* __restrict__ Av,
                                            float* __restrict__ out_me)
{
    const int t    = threadIdx.x;
    const int lane = t & 63;
    const int e    = blockIdx.x * 4 + (t >> 6);  // 4 edges per block, 1 wave each
    int u, v;
    if (e < N_E) { u = src[e]; v = dst[e]; }
    else         { u = dst[e - N_E]; v = src[e - N_E]; }
    const float4 a = *reinterpret_cast<const float4*>(&Au[u * 256 + lane * 4]);
    const float4 b = *reinterpret_cast<const float4*>(&Av[v * 256 + lane * 4]);
    float4 o;
    o.x = leaky(a.x + b.x);
    o.y = leaky(a.y + b.y);
    o.z = leaky(a.z + b.z);
    o.w = leaky(a.w + b.w);
    *reinterpret_cast<float4*>(&out_me[e * 256 + lane * 4]) = o;
}

extern "C" void kernel_launch(void* const* d_in, const int* in_sizes, int n_in,
                              void* d_out, int out_size, void* d_ws, size_t ws_size,
                              hipStream_t stream) {
    const float* hv       = (const float*)d_in[0];
    // d_in[1] he_ftr: unused (align path is dead code — softmax weights sum to 1)
    const float* p_ftr    = (const float*)d_in[2];
    const float* q_ftr    = (const float*)d_in[3];
    const float* vew1     = (const float*)d_in[4];
    const float* vew2     = (const float*)d_in[5];
    // d_in[6], d_in[7] veb1/veb2: redundant with vew
    const float* attend_w = (const float*)d_in[8];
    const float* attend_b = (const float*)d_in[9];
    // d_in[10], d_in[11] align_w/align_b: dead code
    const float* link_w   = (const float*)d_in[12];
    const float* link_b   = (const float*)d_in[13];

    float* out = (float*)d_out;
    float* ws  = (float*)d_ws;

    int*   src    = (int*)ws;              // [0, 8192)
    int*   dst    = src + N_E;             // [8192, 16384)
    int*   indeg  = dst + N_E;             // [16384, 18432)
    float* sumAll = ws + 18432;            // [18432, 18688)
    float* X      = ws + 32768;
    float* Au     = X + N_V * 256;
    float* Av     = Au + N_V * 256;

    // zero indeg + sumAll in one contiguous memset (ws is poisoned to 0xAA)
    (void)hipMemsetAsync(indeg, 0, (N_V + 256) * sizeof(int), stream);

    k_scan<<<2 * SCAN_BPM, 256, 0, stream>>>((const u32x4*)vew1,
                                             (const u32x4*)vew2, src, dst);

    k_gemm<<<dim3(N_V / GEMM_ROWS, 3), 256, 0, stream>>>(hv, attend_w, attend_b,
                                                         link_w, link_b, p_ftr,
                                                         q_ftr, X, Au, Av, out);

    k_indeg<<<N_E / 256, 256, 0, stream>>>(src, dst, indeg);

    k_sumall<<<32, 256, 0, stream>>>(X, indeg, sumAll);

    k_fix<<<N_V, 256, 0, stream>>>(indeg, sumAll, out);

    k_me<<<(2 * N_E) / 4, 256, 0, stream>>>(src, dst, Au, Av, out + N_V * 256);
}